// Round 2
// baseline (222.395 us; speedup 1.0000x reference)
//
#include <hip/hip_runtime.h>
#include <cstdint>
#include <cstddef>

#define S_LEN 4096
#define DMODEL 1024
#define NHEADS 16
#define HDK 64
#define DKV 256
#define NTOT 1536  // 1024 Q + 256 K + 256 V packed N
// SCALE * log2(e), folded into Q projection epilogue so softmax is exp2(s)
#define QSCALE 0.18033688011112042f

typedef __bf16 bf16;
typedef __bf16 bf16x8 __attribute__((ext_vector_type(8)));
typedef float f32x4 __attribute__((ext_vector_type(4)));
typedef float f32x16 __attribute__((ext_vector_type(16)));
typedef unsigned u32x2 __attribute__((ext_vector_type(2)));
typedef unsigned u32x4 __attribute__((ext_vector_type(4)));
typedef unsigned short u16x4 __attribute__((ext_vector_type(4)));

typedef __attribute__((address_space(3))) void lds_void;
typedef const __attribute__((address_space(1))) void gbl_void;

// async global->LDS, 16B/lane, dest = wave-uniform base + lane*16
__device__ __forceinline__ void gload16(const void* g, void* l) {
  __builtin_amdgcn_global_load_lds((gbl_void*)g, (lds_void*)l, 16, 0, 0);
}

// ---------------- fused prep: weight transposes + x downconvert + mask ----------------
__global__ __launch_bounds__(256) void prep(
    const float* __restrict__ x, const int* __restrict__ mask,
    const float* __restrict__ Wq, const float* __restrict__ Wk,
    const float* __restrict__ Wv, const float* __restrict__ Wo,
    bf16* __restrict__ xb, float* __restrict__ mkf, bf16* __restrict__ mkb,
    bf16* __restrict__ Wqt, bf16* __restrict__ Wkt,
    bf16* __restrict__ Wvt, bf16* __restrict__ Wot) {
  const int z = blockIdx.z;
  if (z < 4) {
    const float* src;
    bf16* dst;
    int C;
    switch (z) {
      case 0: src = Wq; dst = Wqt; C = DMODEL; break;
      case 1: src = Wk; dst = Wkt; C = DKV; break;
      case 2: src = Wv; dst = Wvt; C = DKV; break;
      default: src = Wo; dst = Wot; C = DMODEL; break;
    }
    const int c0 = blockIdx.x * 32;
    if (c0 >= C) return;
    __shared__ float tile[32][33];
    const int tx = threadIdx.x & 31;
    const int ty = threadIdx.x >> 5;
    const int r0 = blockIdx.y * 32;
#pragma unroll
    for (int i = 0; i < 4; i++)
      tile[ty + i * 8][tx] = src[(size_t)(r0 + ty + i * 8) * C + c0 + tx];
    __syncthreads();
#pragma unroll
    for (int i = 0; i < 4; i++)
      dst[(size_t)(c0 + ty + i * 8) * DMODEL + r0 + tx] = (bf16)tile[tx][ty + i * 8];
  } else {
    const int b = blockIdx.y * 32 + blockIdx.x;           // 0..1023
    const int half = z - 4;                               // 0 or 1
    const int i = ((half * 1024 + b) * 256 + (int)threadIdx.x) * 8;
    float4 a = *(const float4*)(x + i);
    float4 c = *(const float4*)(x + i + 4);
    bf16 o[8] = {(bf16)a.x, (bf16)a.y, (bf16)a.z, (bf16)a.w,
                 (bf16)c.x, (bf16)c.y, (bf16)c.z, (bf16)c.w};
    *(uint4*)(xb + i) = *(uint4*)o;
    if (half == 1 && b < 2) {
      const int mi = (b * 256 + (int)threadIdx.x) * 8;
#pragma unroll
      for (int j = 0; j < 8; j++) {
        float keep = mask[mi + j] ? 0.0f : 1.0f;
        mkf[mi + j] = keep;
        mkb[mi + j] = (bf16)keep;
      }
    }
  }
}

// ---------------- GEMM: 64x128 tile, BK=64, async DMA, XCD-aware scheduling ----------------
template <int QKV>
__global__ __launch_bounds__(256) void gemm_ld(
    const bf16* __restrict__ A, const bf16* __restrict__ Bt, int M, int N, int K,
    int NT,  // n-tile count = N/128
    const float* __restrict__ bq, const float* __restrict__ bk,
    const float* __restrict__ bv, const float* __restrict__ mkf,
    bf16* __restrict__ Qb, bf16* __restrict__ Kb, bf16* __restrict__ Vtb,
    const float* __restrict__ bo, float* __restrict__ Co) {
  __shared__ bf16 As[64 * 64];
  __shared__ bf16 Bs[128 * 64];
  const int t = threadIdx.x;
  const int lane = t & 63;
  const int wave = t >> 6;

  const int bid = blockIdx.x;
  const int xcd = bid & 7;
  const int local = bid >> 3;
  const int m_local = local / NT;
  const int ntile = local - m_local * NT;
  const int mchunk = (M >> 6) >> 3;  // m-tiles per XCD
  const int m0 = (xcd * mchunk + m_local) * 64;
  const int n0 = ntile * 128;

  const int wm = (wave >> 1) * 32;
  const int wn = (wave & 1) * 64;
  const int lr = lane & 15;
  const int quad = lane >> 4;

  const int sr = lane >> 3;                                // 0..7
  const int sc = ((lane & 7) ^ (lane >> 3)) * 8;           // bf16 offset in 64-K slab

  f32x4 acc[2][4] = {};

  for (int k0 = 0; k0 < K; k0 += 64) {
    __syncthreads();
#pragma unroll
    for (int j = 0; j < 2; j++) {
      const int rbase = wave * 16 + j * 8;
      gload16(A + (size_t)(m0 + rbase + sr) * K + k0 + sc, &As[rbase * 64]);
    }
#pragma unroll
    for (int j = 0; j < 4; j++) {
      const int rbase = wave * 32 + j * 8;
      gload16(Bt + (size_t)(n0 + rbase + sr) * K + k0 + sc, &Bs[rbase * 64]);
    }
    __syncthreads();
#pragma unroll
    for (int kh2 = 0; kh2 < 2; kh2++) {
      const int fo = ((kh2 * 4 + quad) ^ (lr & 7)) * 8;  // swizzled chunk offset
      bf16x8 af[2], bfr[4];
#pragma unroll
      for (int mt = 0; mt < 2; mt++)
        af[mt] = *(const bf16x8*)(&As[(wm + mt * 16 + lr) * 64 + fo]);
#pragma unroll
      for (int nt = 0; nt < 4; nt++)
        bfr[nt] = *(const bf16x8*)(&Bs[(wn + nt * 16 + lr) * 64 + fo]);
#pragma unroll
      for (int mt = 0; mt < 2; mt++)
#pragma unroll
        for (int nt = 0; nt < 4; nt++)
          acc[mt][nt] = __builtin_amdgcn_mfma_f32_16x16x32_bf16(af[mt], bfr[nt], acc[mt][nt], 0, 0, 0);
    }
  }

#pragma unroll
  for (int nt = 0; nt < 4; nt++) {
    const int n = n0 + wn + nt * 16 + lr;
    if (QKV) {
      if (n < DMODEL) {
        const float b = bq[n];
#pragma unroll
        for (int mt = 0; mt < 2; mt++)
#pragma unroll
          for (int r = 0; r < 4; r++) {
            const int m = m0 + wm + mt * 16 + quad * 4 + r;
            Qb[(size_t)m * DMODEL + n] = (bf16)((acc[mt][nt][r] + b) * QSCALE);
          }
      } else if (n < DMODEL + DKV) {
        const float b = bk[n - DMODEL];
#pragma unroll
        for (int mt = 0; mt < 2; mt++)
#pragma unroll
          for (int r = 0; r < 4; r++) {
            const int m = m0 + wm + mt * 16 + quad * 4 + r;
            Kb[(size_t)m * DKV + (n - DMODEL)] = (bf16)(acc[mt][nt][r] + b);
          }
      } else {
        const float b = bv[n - DMODEL - DKV];
#pragma unroll
        for (int mt = 0; mt < 2; mt++)
#pragma unroll
          for (int r = 0; r < 4; r++) {
            const int m = m0 + wm + mt * 16 + quad * 4 + r;
            Vtb[(size_t)(n - DMODEL - DKV) * S_LEN + m] = (bf16)((acc[mt][nt][r] + b) * mkf[m]);
          }
      }
    } else {
      const float b = bo[n];
#pragma unroll
      for (int mt = 0; mt < 2; mt++)
#pragma unroll
        for (int r = 0; r < 4; r++) {
          const int m = m0 + wm + mt * 16 + quad * 4 + r;
          Co[(size_t)m * N + n] = acc[mt][nt][r] + b;
        }
    }
  }
}

// ---------------- flash attention: 32x32 MFMA core, in-register P via permlane32_swap ----------------
// S^T(32k x 32q) = K-tile x Q^T; C layout: col=q=lane&31, row=key=(r&3)+8*(r>>2)+4*hi.
// P^T k-slice B-fragments built in-register: pack exp2 results of consecutive-key pairs into
// bf16x2 words, then __builtin_amdgcn_permlane32_swap (upper-half of arg0 <-> lower-half of arg1)
// produces both B-fragment words per swap. PV computed as O^T = V^T x P^T; row-sum l via
// mask-broadcast A-operand MFMA reusing the same P^T B-fragments.
// K/V staging + XOR chunk swizzle + async-DMA double buffer identical to R10-validated version.
__global__ __launch_bounds__(256) void flash_attn(
    const bf16* __restrict__ Q, const bf16* __restrict__ K,
    const bf16* __restrict__ Vt, const bf16* __restrict__ mkb,
    bf16* __restrict__ O) {
  const int h = blockIdx.y;
  const int kvh = h >> 2;
  const int q0 = blockIdx.x * 128;
  const int t = threadIdx.x;
  const int lane = t & 63;
  const int wave = t >> 6;
  const int l31 = lane & 31;
  const int hi = lane >> 5;

  __shared__ bf16 Ks[2][128 * 64];   // 32 KB  [key][d], chunk^(key&7) swizzle
  __shared__ bf16 Vs[2][64 * 128];   // 32 KB  [d][key], chunk^(d&15) swizzle

  // Q fragments (B-operand of QK^T): aq[s] holds Q[qrow][s*16 + hi*8 + j]
  const int qrow = q0 + wave * 32 + l31;
  bf16x8 aq[4];
  {
    const bf16* qp = Q + (size_t)qrow * DMODEL + h * HDK + hi * 8;
#pragma unroll
    for (int s = 0; s < 4; s++) aq[s] = *(const bf16x8*)(qp + s * 16);
  }

  const bf16* Kg = K + kvh * HDK;
  const bf16* Vg = Vt + (size_t)kvh * HDK * S_LEN;
  const int krl = lane >> 3;
  const int kgc = ((lane & 7) ^ (lane >> 3)) * 8;
  const int vrl = lane >> 4;

  // prologue: stage tile 0 into buf 0
#pragma unroll
  for (int j = 0; j < 4; j++) {
    const int rb = wave * 32 + j * 8;
    gload16(Kg + (size_t)(rb + krl) * DKV + kgc, &Ks[0][rb * 64]);
  }
#pragma unroll
  for (int j = 0; j < 4; j++) {
    const int rb = wave * 16 + j * 4;
    const int g = ((lane & 15) ^ (j * 4 + vrl)) * 8;
    gload16(Vg + (size_t)(rb + vrl) * S_LEN + g, &Vs[0][rb * 128]);
  }

  f32x16 o_acc[2] = {};  // O^T: row d = dt*32 + (r&3)+8*(r>>2)+4*hi, col q = l31
  f32x16 l_acc = {};     // all rows equal; col q = l31
  int buf = 0;

  for (int kv0 = 0; kv0 < S_LEN; kv0 += 128) {
    __syncthreads();  // drains this tile's DMA + prev tile's LDS reads
    const int kvn = kv0 + 128;
    if (kvn < S_LEN) {
      const int nb = buf ^ 1;
#pragma unroll
      for (int j = 0; j < 4; j++) {
        const int rb = wave * 32 + j * 8;
        gload16(Kg + (size_t)(kvn + rb + krl) * DKV + kgc, &Ks[nb][rb * 64]);
      }
#pragma unroll
      for (int j = 0; j < 4; j++) {
        const int rb = wave * 16 + j * 4;
        const int g = ((lane & 15) ^ (j * 4 + vrl)) * 8;
        gload16(Vg + (size_t)(rb + vrl) * S_LEN + kvn + g, &Vs[nb][rb * 128]);
      }
    }
    const bf16* Ksb = Ks[buf];
    const bf16* Vsb = Vs[buf];

#pragma unroll
    for (int t4 = 0; t4 < 4; t4++) {
      // --- QK^T: one 32x32 S^T tile, K-dim 64 = 4 slices of 16 ---
      const int key = t4 * 32 + l31;
      bf16x8 akf[4];
#pragma unroll
      for (int s = 0; s < 4; s++)
        akf[s] = *(const bf16x8*)(&Ksb[key * 64 + ((s * 2 + hi) ^ (key & 7)) * 8]);
      f32x16 sa = {};
      __builtin_amdgcn_s_setprio(1);
#pragma unroll
      for (int s = 0; s < 4; s++)
        sa = __builtin_amdgcn_mfma_f32_32x32x16_bf16(akf[s], aq[s], sa, 0, 0, 0);
      __builtin_amdgcn_s_setprio(0);

      // --- softmax: P = exp2(s); pack consecutive-key pairs into bf16x2 words ---
      // pw[i] holds keys (2i-pair) for this lane-half: key_local = (r&3)+8*(r>>2)+4*hi
      unsigned pw[8];
#pragma unroll
      for (int i = 0; i < 8; i++) {
        const bf16 e0 = (bf16)__builtin_amdgcn_exp2f(sa[2 * i]);
        const bf16 e1 = (bf16)__builtin_amdgcn_exp2f(sa[2 * i + 1]);
        pw[i] = ((unsigned)__builtin_bit_cast(unsigned short, e1) << 16) |
                (unsigned)__builtin_bit_cast(unsigned short, e0);
      }
      // lane-half exchange: upper half of arg0 <-> lower half of arg1.
      // s02 = {new pw0, new pw2}: pw0' = keys 0..7 rows both halves, pw2' = keys 8..15 etc.
      const u32x2 s02 = __builtin_amdgcn_permlane32_swap(pw[0], pw[2], false, false);
      const u32x2 s13 = __builtin_amdgcn_permlane32_swap(pw[1], pw[3], false, false);
      const u32x2 s46 = __builtin_amdgcn_permlane32_swap(pw[4], pw[6], false, false);
      const u32x2 s57 = __builtin_amdgcn_permlane32_swap(pw[5], pw[7], false, false);
      const u32x4 b0v = {s02[0], s13[0], s02[1], s13[1]};
      const u32x4 b1v = {s46[0], s57[0], s46[1], s57[1]};
      const bf16x8 bp0 = __builtin_bit_cast(bf16x8, b0v);  // P^T keys t4*32+0..15
      const bf16x8 bp1 = __builtin_bit_cast(bf16x8, b1v);  // P^T keys t4*32+16..31

      // --- PV: O^T += V^T * P^T ; l += mk * P^T (mk broadcast A-operand) ---
      const bf16x8 amk0 = *(const bf16x8*)(mkb + kv0 + t4 * 32 + hi * 8);
      const bf16x8 amk1 = *(const bf16x8*)(mkb + kv0 + t4 * 32 + 16 + hi * 8);
      __builtin_amdgcn_s_setprio(1);
#pragma unroll
      for (int dt = 0; dt < 2; dt++) {
        const int d = dt * 32 + l31;
        const bf16x8 av0 = *(const bf16x8*)(&Vsb[d * 128 + ((t4 * 4 + hi) ^ (d & 15)) * 8]);
        const bf16x8 av1 = *(const bf16x8*)(&Vsb[d * 128 + ((t4 * 4 + 2 + hi) ^ (d & 15)) * 8]);
        o_acc[dt] = __builtin_amdgcn_mfma_f32_32x32x16_bf16(av0, bp0, o_acc[dt], 0, 0, 0);
        o_acc[dt] = __builtin_amdgcn_mfma_f32_32x32x16_bf16(av1, bp1, o_acc[dt], 0, 0, 0);
      }
      l_acc = __builtin_amdgcn_mfma_f32_32x32x16_bf16(amk0, bp0, l_acc, 0, 0, 0);
      l_acc = __builtin_amdgcn_mfma_f32_32x32x16_bf16(amk1, bp1, l_acc, 0, 0, 0);
      __builtin_amdgcn_s_setprio(0);
    }
    buf ^= 1;
  }

  // epilogue: O^T regs -> O[qrow][h*64+d], packed 8B stores (d = 8g + 4hi + j)
  const float linv = 1.0f / l_acc[0];
  bf16* Orow = O + (size_t)qrow * DMODEL + h * HDK;
#pragma unroll
  for (int dt = 0; dt < 2; dt++) {
#pragma unroll
    for (int g = 0; g < 4; g++) {
      u16x4 o4;
#pragma unroll
      for (int j = 0; j < 4; j++)
        o4[j] = __builtin_bit_cast(unsigned short, (bf16)(o_acc[dt][g * 4 + j] * linv));
      *(u16x4*)(Orow + dt * 32 + g * 8 + hi * 4) = o4;
    }
  }
}

// ---------------- launch ----------------
extern "C" void kernel_launch(void* const* d_in, const int* in_sizes, int n_in,
                              void* d_out, int out_size, void* d_ws, size_t ws_size,
                              hipStream_t stream) {
  const float* x = (const float*)d_in[0];
  const int* mask = (const int*)d_in[1];
  const float* Wq = (const float*)d_in[2];
  const float* bq = (const float*)d_in[3];
  const float* Wk = (const float*)d_in[4];
  const float* bk = (const float*)d_in[5];
  const float* Wv = (const float*)d_in[6];
  const float* bv = (const float*)d_in[7];
  const float* Wo = (const float*)d_in[8];
  const float* bo = (const float*)d_in[9];
  float* out = (float*)d_out;

  char* w = (char*)d_ws;
  bf16* xb  = (bf16*)w; w += (size_t)S_LEN * DMODEL * 2;
  bf16* Wqt = (bf16*)w; w += (size_t)DMODEL * DMODEL * 2;  // packed B rows 0..1023
  bf16* Wkt = (bf16*)w; w += (size_t)DKV * DMODEL * 2;     // rows 1024..1279
  bf16* Wvt = (bf16*)w; w += (size_t)DKV * DMODEL * 2;     // rows 1280..1535
  bf16* Wot = (bf16*)w; w += (size_t)DMODEL * DMODEL * 2;
  bf16* Qb  = (bf16*)w; w += (size_t)S_LEN * DMODEL * 2;
  bf16* Kb  = (bf16*)w; w += (size_t)S_LEN * DKV * 2;
  bf16* Vtb = (bf16*)w; w += (size_t)DKV * S_LEN * 2;
  bf16* Ob  = (bf16*)w; w += (size_t)S_LEN * DMODEL * 2;
  float* mkf = (float*)w; w += (size_t)S_LEN * 4;
  bf16* mkb = (bf16*)w; w += (size_t)S_LEN * 2;

  // fused prep (1 dispatch): transposes + x convert + mask
  prep<<<dim3(32, 32, 6), 256, 0, stream>>>(
      x, mask, Wq, Wk, Wv, Wo, xb, mkf, mkb, Wqt, Wkt, Wvt, Wot);

  // fused QKV projection (packed N = 1536), XCD-scheduled 1D grid 768
  gemm_ld<1><<<dim3((S_LEN / 64) * (NTOT / 128)), 256, 0, stream>>>(
      xb, Wqt, S_LEN, NTOT, DMODEL, NTOT / 128, bq, bk, bv, mkf, Qb, Kb, Vtb,
      nullptr, nullptr);

  // attention
  flash_attn<<<dim3(S_LEN / 128, NHEADS), 256, 0, stream>>>(Qb, Kb, Vtb, mkb, Ob);

  // output projection (fp32 out), XCD-scheduled 1D grid 512
  gemm_ld<0><<<dim3((S_LEN / 64) * (DMODEL / 128)), 256, 0, stream>>>(
      Ob, Wot, S_LEN, DMODEL, DMODEL, DMODEL / 128, nullptr, nullptr, nullptr,
      nullptr, nullptr, nullptr, nullptr, bo, out);
}